// Round 2
// baseline (216.792 us; speedup 1.0000x reference)
//
#include <hip/hip_runtime.h>

#define EPSF 1e-7f

// Repack conv_w [co][ci][3][3] -> wT [ci][tap][co]  (147456 floats, lives in d_ws)
__global__ void repack_w_kernel(const float* __restrict__ cw, float* __restrict__ wT) {
    int idx = blockIdx.x * 256 + threadIdx.x;
    if (idx >= 128 * 9 * 128) return;
    int co  = idx & 127;
    int tap = (idx >> 7) % 9;
    int ci  = idx / (128 * 9);
    wT[idx] = cw[(co * 128 + ci) * 9 + tap];
}

// One block per (b, h): computes y[b, 0:128, h, 0:64] (3x3 conv + bias) and the
// fused squash over do-groups of 16, writing out[b, mo, h, w, do].
// Thread tile: 8 co x 4 w. K-loop: 16 chunks of 8 ci.
__global__ __launch_bounds__(256, 2) void conv_squash_kernel(
    const float* __restrict__ x,     // [8,8,64,64,16]  (b, mi, h, w, di)
    const float* __restrict__ wT,    // [128][9][128]   (ci, tap, co)
    const float* __restrict__ bias,  // [128]
    float* __restrict__ out)         // [8,8,64,64,16]  (b, mo, h, w, do)
{
    __shared__ float lds_in[8][3][68];     // [ci_l][row][wi]  wi = w+1, 66 used
    __shared__ float lds_w[8 * 9 * 128];   // [ci_l][tap][co] contiguous

    const int blk = blockIdx.x;
    const int b = blk >> 6;
    const int h = blk & 63;
    const int tid = (int)threadIdx.x;
    const int cg = tid >> 4;     // 0..15 co-group
    const int wg = tid & 15;     // 0..15 w-group
    const int co0 = cg << 3;
    const int w0 = wg << 2;

    float acc[8][4];
#pragma unroll
    for (int c = 0; c < 8; ++c) {
        const float bv = bias[co0 + c];
#pragma unroll
        for (int j = 0; j < 4; ++j) acc[c][j] = bv;
    }

    for (int ch = 0; ch < 16; ++ch) {
        const int ci0 = ch << 3;
        const int mi  = ci0 >> 4;      // ci = mi*16 + di
        const int di0 = ci0 & 15;      // 0 or 8
        __syncthreads();
        // ---- stage input chunk: 8 ci x 3 rows x 66 w (zero-padded halo) ----
        for (int e = tid; e < 8 * 3 * 66; e += 256) {
            const int cil = e / 198;
            const int rem = e - cil * 198;
            const int r   = rem / 66;
            const int wi  = rem - r * 66;
            const int gw  = wi - 1;
            const int gh  = h + r - 1;
            float v = 0.0f;
            if ((unsigned)gw < 64u && (unsigned)gh < 64u)
                v = x[((((b * 8 + mi) * 64 + gh) * 64 + gw) << 4) + di0 + cil];
            lds_in[cil][r][wi] = v;
        }
        // ---- stage weight chunk: contiguous 9216-float copy (coalesced, no conflicts) ----
        const float* wsrc = wT + ci0 * 9 * 128;
#pragma unroll 4
        for (int e = tid; e < 8 * 9 * 128; e += 256)
            lds_w[e] = wsrc[e];
        __syncthreads();

        // ---- compute: 2304 FMAs per thread per chunk ----
        for (int cil = 0; cil < 8; ++cil) {
#pragma unroll
            for (int kh = 0; kh < 3; ++kh) {
                const float4 i0 = *(const float4*)&lds_in[cil][kh][w0];
                const float2 i1 = *(const float2*)&lds_in[cil][kh][w0 + 4];
                const float vals[6] = { i0.x, i0.y, i0.z, i0.w, i1.x, i1.y };
#pragma unroll
                for (int kw = 0; kw < 3; ++kw) {
                    const int wrow = ((cil * 9 + kh * 3 + kw) << 7) + co0;
                    const float4 wa = *(const float4*)&lds_w[wrow];
                    const float4 wb = *(const float4*)&lds_w[wrow + 4];
                    const float wv[8] = { wa.x, wa.y, wa.z, wa.w, wb.x, wb.y, wb.z, wb.w };
#pragma unroll
                    for (int c = 0; c < 8; ++c) {
#pragma unroll
                        for (int j = 0; j < 4; ++j)
                            acc[c][j] = fmaf(wv[c], vals[j + kw], acc[c][j]);
                    }
                }
            }
        }
    }

    // ---- fused squash epilogue ----
    // This thread holds co0..co0+7 = half of output-map mo = cg>>1.
    // Partner thread (tid^16) holds the other half of the 16-dim capsule.
    const int mo  = cg >> 1;
    const int do0 = (cg & 1) << 3;
    float mult[4];
#pragma unroll
    for (int j = 0; j < 4; ++j) {
        float s = 0.0f;
#pragma unroll
        for (int c = 0; c < 8; ++c) s = fmaf(acc[c][j], acc[c][j], s);
        const float tot = s + __shfl_xor(s, 16, 64);
        // squash multiplier: (|v|^2/(1+|v|^2)) / sqrt(|v|^2+eps)
        mult[j] = tot / ((1.0f + tot) * sqrtf(tot + EPSF));
    }
#pragma unroll
    for (int j = 0; j < 4; ++j) {
        float4 o0, o1;
        o0.x = acc[0][j] * mult[j];
        o0.y = acc[1][j] * mult[j];
        o0.z = acc[2][j] * mult[j];
        o0.w = acc[3][j] * mult[j];
        o1.x = acc[4][j] * mult[j];
        o1.y = acc[5][j] * mult[j];
        o1.z = acc[6][j] * mult[j];
        o1.w = acc[7][j] * mult[j];
        const int base = ((((b * 8 + mo) * 64 + h) * 64 + (w0 + j)) << 4) + do0;
        *(float4*)&out[base]     = o0;
        *(float4*)&out[base + 4] = o1;
    }
}

extern "C" void kernel_launch(void* const* d_in, const int* in_sizes, int n_in,
                              void* d_out, int out_size, void* d_ws, size_t ws_size,
                              hipStream_t stream) {
    const float* x  = (const float*)d_in[0];
    const float* cw = (const float*)d_in[1];
    const float* cb = (const float*)d_in[2];
    // d_in[3] (b_logits) is mathematically irrelevant: softmax over the MI axis of a
    // broadcast (size-1) pred axis is shift-invariant and sums to 1 -> out = squash(pred).
    float* outp = (float*)d_out;
    float* wT   = (float*)d_ws;  // 589,824 bytes

    hipLaunchKernelGGL(repack_w_kernel, dim3(576), dim3(256), 0, stream, cw, wT);
    hipLaunchKernelGGL(conv_squash_kernel, dim3(512), dim3(256), 0, stream,
                       x, wT, cb, outp);
}

// Round 8
// 94.983 us; speedup vs baseline: 2.2824x; 2.2824x over previous
//
#include <hip/hip_runtime.h>

#define EPSF 1e-7f

typedef _Float16 f16x8 __attribute__((ext_vector_type(8)));
typedef float f32x4 __attribute__((ext_vector_type(4)));

#define LDS_A_BYTES 67584          // 4 rows * 16 g * 66 w' * 16B
#define LDS_B_BYTES 32768          // per buffer: 16 g * 128 co * 16B
#define LDS_TOTAL (LDS_A_BYTES + 2 * LDS_B_BYTES)  // 133120

// ---------------------------------------------------------------------------
// repack: conv_w fp32 [co][ci][3][3] -> wTh f16, linear image of the B LDS
// layout: e = ((tap*16 + g)*128 + co)*8 + sub, ci = g*8 + sub.
// ---------------------------------------------------------------------------
__global__ void repack_kernel(const float* __restrict__ cw, _Float16* __restrict__ wTh) {
    int e = blockIdx.x * 256 + threadIdx.x;
    if (e >= 9 * 16 * 128 * 8) return;
    int sub = e & 7;
    int co  = (e >> 3) & 127;
    int g   = (e >> 10) & 15;
    int t   = e >> 14;
    wTh[e] = (_Float16)cw[(co * 128 + (g * 8 + sub)) * 9 + t];
}

// ---------------------------------------------------------------------------
// Implicit-GEMM conv + fused squash. One block per (b, output-row-pair).
// M=128 pixels (2 rows x 64 w), N=128 co, K = 9 taps x 128 ci.
// 4 waves, each a 64x64 tile via mfma_f32_16x16x32_f16.
// A LDS [r][g][w']: byte = r*16896 + g*1056 + wp*16 (g = ci>>3) -> A-frag
//   ds_read_b128 16-lane-contiguous, conflict-free.
// B LDS [g][co]: byte = g*2048 + co*16 per 32KB tap buffer; wave reads its
//   co half at + wave_n*1024.  <-- THE r5/r7 BUG: this offset was missing,
//   both waves read co 0-63 (identical absmax across staging mechanisms
//   proved staging + C/D layout were innocent; only this term was left).
// B staging: reg-staged ds_write, write-late double buffer: load regs(t+1)
//   early, ds_write after MFMA, one barrier per tap. Read buffer buf[t&1]
//   and write buffer buf[(t+1)&1] disjoint; reuse barrier-separated.
// ---------------------------------------------------------------------------
__global__ __launch_bounds__(256, 1) void conv_mfma_kernel(
    const float* __restrict__ x,      // [8,8,64,64,16] fp32
    const _Float16* __restrict__ wTh, // repacked weights (d_ws)
    const float* __restrict__ bias,   // [128] fp32
    float* __restrict__ out)          // [8,8,64,64,16] fp32
{
    extern __shared__ char smem[];
    char* A = smem;
    char* Bb[2] = { smem + LDS_A_BYTES, smem + LDS_A_BYTES + LDS_B_BYTES };

    const int tid  = (int)threadIdx.x;
    const int lane = tid & 63;
    const int w_id = tid >> 6;
    const int q    = lane >> 4;
    const int m15  = lane & 15;
    const int blk  = (int)blockIdx.x;
    const int b    = blk >> 5;
    const int h0   = (blk & 31) << 1;

    // ---- prologue: tap-0 weights -> regs (16B/thread/iter, coalesced) ----
    f16x8 breg[8];
#pragma unroll
    for (int it = 0; it < 8; ++it)
        breg[it] = *(const f16x8*)(wTh + (tid + it * 256) * 8);

    // ---- A staging: 4 input rows, fp32 -> f16, zero halo ----
    for (int i = 0; i < 17; ++i) {
        const int gi = tid + i * 256;
        if (gi < 4224) {
            const int g  = gi & 15;
            const int rw = gi >> 4;
            const int r  = rw / 66;
            const int wp = rw - r * 66;
            const int mi = g >> 1, di0 = (g & 1) << 3;
            const int gh = h0 - 1 + r, gw = wp - 1;
            f16x8 v = {0, 0, 0, 0, 0, 0, 0, 0};
            if ((unsigned)gh < 64u && (unsigned)gw < 64u) {
                const float* xp = x + ((((b * 8 + mi) * 64 + gh) * 64 + gw) * 16 + di0);
                const float4 lo = *(const float4*)xp;
                const float4 hi = *(const float4*)(xp + 4);
                v[0] = (_Float16)lo.x; v[1] = (_Float16)lo.y;
                v[2] = (_Float16)lo.z; v[3] = (_Float16)lo.w;
                v[4] = (_Float16)hi.x; v[5] = (_Float16)hi.y;
                v[6] = (_Float16)hi.z; v[7] = (_Float16)hi.w;
            }
            *(f16x8*)(A + r * 16896 + g * 1056 + wp * 16) = v;
        }
    }

    // ---- write tap-0 weights into buffer 0 (linear, conflict-free) ----
#pragma unroll
    for (int it = 0; it < 8; ++it)
        *(f16x8*)(Bb[0] + (tid + it * 256) * 16) = breg[it];

    __syncthreads();  // A + B0 visible to all waves

    const int wave_m = w_id >> 1, wave_n = w_id & 1;
    const char* aptr = A + wave_m * 16896 + q * 1056 + m15 * 16;

    f32x4 acc[4][4];
#pragma unroll
    for (int fn = 0; fn < 4; ++fn) {
        const float bv = bias[wave_n * 64 + fn * 16 + m15];
#pragma unroll
        for (int fm = 0; fm < 4; ++fm) {
            acc[fm][fn][0] = bv; acc[fm][fn][1] = bv;
            acc[fm][fn][2] = bv; acc[fm][fn][3] = bv;
        }
    }

    // ---- K loop: 9 taps x (4 k-steps of K=32) ----
#pragma unroll
    for (int kh = 0; kh < 3; ++kh) {
#pragma unroll
        for (int kw = 0; kw < 3; ++kw) {
            const int t = kh * 3 + kw;
            // issue next tap's weight loads early (latency hidden under MFMA)
            if (t < 8) {
#pragma unroll
                for (int it = 0; it < 8; ++it)
                    breg[it] = *(const f16x8*)(wTh + (t + 1) * 16384 + (tid + it * 256) * 8);
            }
            // wave_n*1024 selects this wave's 64-co half (the fix)
            const char* bptr = Bb[t & 1] + q * 2048 + wave_n * 1024 + m15 * 16;
            const char* ap   = aptr + kh * 16896 + kw * 16;
#pragma unroll
            for (int kc = 0; kc < 4; ++kc) {
                f16x8 bf[4], af[4];
#pragma unroll
                for (int fn = 0; fn < 4; ++fn)
                    bf[fn] = *(const f16x8*)(bptr + kc * 8192 + fn * 256);
#pragma unroll
                for (int fm = 0; fm < 4; ++fm)
                    af[fm] = *(const f16x8*)(ap + kc * 4224 + fm * 256);
#pragma unroll
                for (int fm = 0; fm < 4; ++fm)
#pragma unroll
                    for (int fn = 0; fn < 4; ++fn)
                        acc[fm][fn] = __builtin_amdgcn_mfma_f32_16x16x32_f16(
                            af[fm], bf[fn], acc[fm][fn], 0, 0, 0);
            }
            // write next tap into the other buffer (disjoint from bptr's buffer)
            if (t < 8) {
                char* wb = Bb[(t + 1) & 1];
#pragma unroll
                for (int it = 0; it < 8; ++it)
                    *(f16x8*)(wb + (tid + it * 256) * 16) = breg[it];
            }
            __syncthreads();  // reads of buf[t&1] done; buf[(t+1)&1] visible
        }
    }

    // ---- fused squash epilogue via LDS transpose (dead A/B space) ----
    char* Y = smem + w_id * 17408;  // per-wave 64 px x 68 floats (272B rows)
#pragma unroll
    for (int fm = 0; fm < 4; ++fm)
#pragma unroll
        for (int fn = 0; fn < 4; ++fn)
#pragma unroll
            for (int rg = 0; rg < 4; ++rg) {
                const int m = fm * 16 + q * 4 + rg;   // pixel w (C/D row)
                const int c = fn * 16 + m15;          // local co (C/D col)
                *(float*)(Y + m * 272 + c * 4) = acc[fm][fn][rg];
            }
    __syncthreads();

    const int h = h0 + wave_m;
#pragma unroll
    for (int i = 0; i < 4; ++i) {
        const int m   = i * 16 + m15;  // w
        const int mol = q;             // local mo (0..3)
        const float* yp = (const float*)(Y + m * 272 + mol * 64);
        float4 v0 = *(const float4*)(yp);
        float4 v1 = *(const float4*)(yp + 4);
        float4 v2 = *(const float4*)(yp + 8);
        float4 v3 = *(const float4*)(yp + 12);
        float s = 0.f;
        s = fmaf(v0.x, v0.x, s); s = fmaf(v0.y, v0.y, s);
        s = fmaf(v0.z, v0.z, s); s = fmaf(v0.w, v0.w, s);
        s = fmaf(v1.x, v1.x, s); s = fmaf(v1.y, v1.y, s);
        s = fmaf(v1.z, v1.z, s); s = fmaf(v1.w, v1.w, s);
        s = fmaf(v2.x, v2.x, s); s = fmaf(v2.y, v2.y, s);
        s = fmaf(v2.z, v2.z, s); s = fmaf(v2.w, v2.w, s);
        s = fmaf(v3.x, v3.x, s); s = fmaf(v3.y, v3.y, s);
        s = fmaf(v3.z, v3.z, s); s = fmaf(v3.w, v3.w, s);
        const float mult = s / ((1.0f + s) * sqrtf(s + EPSF));
        v0.x *= mult; v0.y *= mult; v0.z *= mult; v0.w *= mult;
        v1.x *= mult; v1.y *= mult; v1.z *= mult; v1.w *= mult;
        v2.x *= mult; v2.y *= mult; v2.z *= mult; v2.w *= mult;
        v3.x *= mult; v3.y *= mult; v3.z *= mult; v3.w *= mult;
        const int mo = wave_n * 4 + mol;
        float* op = out + ((((b * 8 + mo) * 64 + h) * 64 + m) * 16);
        *(float4*)(op)      = v0;
        *(float4*)(op + 4)  = v1;
        *(float4*)(op + 8)  = v2;
        *(float4*)(op + 12) = v3;
    }
}

extern "C" void kernel_launch(void* const* d_in, const int* in_sizes, int n_in,
                              void* d_out, int out_size, void* d_ws, size_t ws_size,
                              hipStream_t stream) {
    const float* x  = (const float*)d_in[0];
    const float* cw = (const float*)d_in[1];
    const float* cb = (const float*)d_in[2];
    // d_in[3] (b_logits): routing is degenerate (softmax over broadcast size-1
    // MI axis, shift-invariant b-updates) -> out = squash(conv_out). Verified
    // empirically by the passing round-2 fp32 kernel (absmax 0.0039).
    float* outp    = (float*)d_out;
    _Float16* wTh  = (_Float16*)d_ws;  // 294,912 bytes

    hipFuncSetAttribute((const void*)conv_mfma_kernel,
                        hipFuncAttributeMaxDynamicSharedMemorySize, LDS_TOTAL);
    hipLaunchKernelGGL(repack_kernel, dim3(576), dim3(256), 0, stream, cw, wTh);
    hipLaunchKernelGGL(conv_mfma_kernel, dim3(256), dim3(256), LDS_TOTAL, stream,
                       x, wTh, cb, outp);
}

// Round 10
// 94.272 us; speedup vs baseline: 2.2996x; 1.0075x over previous
//
#include <hip/hip_runtime.h>

#define EPSF 1e-7f

typedef _Float16 f16x8 __attribute__((ext_vector_type(8)));
typedef float f32x4 __attribute__((ext_vector_type(4)));

#define LDS_A_BYTES 67584          // 4 rows * 16 g * 66 w' * 16B
#define LDS_TOTAL   69632          // max(A, 8 waves * 8704B epilogue scratch)

// ---------------------------------------------------------------------------
// repack: conv_w fp32 [co][ci][3][3] -> wTh f16 in FRAGMENT order:
// e = ((tap*16 + g)*128 + co)*8 + sub, ci = g*8 + sub.
// Conv kernel reads B fragments directly from this image (no LDS for B).
// ---------------------------------------------------------------------------
__global__ void repack_kernel(const float* __restrict__ cw, _Float16* __restrict__ wTh) {
    int e = blockIdx.x * 256 + threadIdx.x;
    if (e >= 9 * 16 * 128 * 8) return;
    int sub = e & 7;
    int co  = (e >> 3) & 127;
    int g   = (e >> 10) & 15;
    int t   = e >> 14;
    wTh[e] = (_Float16)cw[(co * 128 + (g * 8 + sub)) * 9 + t];
}

// ---------------------------------------------------------------------------
// Implicit-GEMM conv + fused squash. One block per (b, output-row-pair).
// M=128 px (2 rows x 64 w), N=128 co, K = 9 taps x 128 ci.
// 512 threads = 8 waves (4m x 2n), wave tile 32x64, mfma_f32_16x16x32_f16.
// vs round-8 (44 us, MfmaUtil 7%, Occ 9% -> latency-bound at 1 wave/SIMD):
//   - B direct global->VGPR from frag-ordered wTh (L2-resident, L1 shared by
//     the 4 m-waves) -> no B LDS, no ds_writes, NO barriers in the K-loop
//     (A-tile is static across taps).
//   - 8 waves/CU = 2/SIMD for TLP.
// A LDS [r][g][w']: byte = r*16896 + g*1056 + wp*16; A-frag ds_read_b128 is
//   16-lane-contiguous (256B runs) -> conflict-free.
// ---------------------------------------------------------------------------
__global__ __launch_bounds__(512, 2) void conv_mfma_kernel(
    const float* __restrict__ x,      // [8,8,64,64,16] fp32
    const _Float16* __restrict__ wTh, // repacked weights (d_ws)
    const float* __restrict__ bias,   // [128] fp32
    float* __restrict__ out)          // [8,8,64,64,16] fp32
{
    extern __shared__ char smem[];
    char* A = smem;

    const int tid  = (int)threadIdx.x;
    const int lane = tid & 63;
    const int w_id = tid >> 6;       // 0..7
    const int q    = lane >> 4;      // 0..3
    const int m15  = lane & 15;
    const int wm   = w_id >> 1;      // 0..3: px window
    const int wn   = w_id & 1;       // 0..1: co window [wn*64, wn*64+64)
    const int blk  = (int)blockIdx.x;
    const int b    = blk >> 5;
    const int h0   = (blk & 31) << 1;

    // ---- A staging: 4 input rows, fp32 -> f16, zero halo ----
    for (int i = 0; i < 9; ++i) {
        const int gi = tid + i * 512;
        if (gi < 4224) {
            const int g  = gi & 15;
            const int rw = gi >> 4;
            const int r  = rw / 66;
            const int wp = rw - r * 66;
            const int mi = g >> 1, di0 = (g & 1) << 3;
            const int gh = h0 - 1 + r, gw = wp - 1;
            f16x8 v = {0, 0, 0, 0, 0, 0, 0, 0};
            if ((unsigned)gh < 64u && (unsigned)gw < 64u) {
                const float* xp = x + ((((b * 8 + mi) * 64 + gh) * 64 + gw) * 16 + di0);
                const float4 lo = *(const float4*)xp;
                const float4 hi = *(const float4*)(xp + 4);
                v[0] = (_Float16)lo.x; v[1] = (_Float16)lo.y;
                v[2] = (_Float16)lo.z; v[3] = (_Float16)lo.w;
                v[4] = (_Float16)hi.x; v[5] = (_Float16)hi.y;
                v[6] = (_Float16)hi.z; v[7] = (_Float16)hi.w;
            }
            *(f16x8*)(A + r * 16896 + g * 1056 + wp * 16) = v;
        }
    }
    __syncthreads();  // A ready; read-only for the whole K loop

    f32x4 acc[2][4];
#pragma unroll
    for (int fn = 0; fn < 4; ++fn) {
        const float bv = bias[wn * 64 + fn * 16 + m15];  // C/D col = m15
#pragma unroll
        for (int fm = 0; fm < 2; ++fm) {
            acc[fm][fn][0] = bv; acc[fm][fn][1] = bv;
            acc[fm][fn][2] = bv; acc[fm][fn][3] = bv;
        }
    }

    // wave's A base: row offset (wm>>1), w offset (wm&1)*32, lane offset m15
    const char* aw = A + (wm >> 1) * 16896 + ((wm & 1) * 32 + m15) * 16;

    // ---- K loop: 9 taps, barrier-free ----
#pragma unroll
    for (int kh = 0; kh < 3; ++kh) {
#pragma unroll
        for (int kw = 0; kw < 3; ++kw) {
            const int t = kh * 3 + kw;
            // B fragments: 16 x 16B direct global loads (frag-ordered image)
            f16x8 bf[4][4];
#pragma unroll
            for (int kc = 0; kc < 4; ++kc)
#pragma unroll
                for (int fn = 0; fn < 4; ++fn)
                    bf[kc][fn] = *(const f16x8*)(wTh +
                        ((size_t)((t * 16 + kc * 4 + q) * 128 + wn * 64 + fn * 16 + m15)) * 8);
#pragma unroll
            for (int kc = 0; kc < 4; ++kc) {
                f16x8 af[2];
#pragma unroll
                for (int fm = 0; fm < 2; ++fm)
                    af[fm] = *(const f16x8*)(aw + kh * 16896 + (kc * 4 + q) * 1056
                                                + (fm * 16 + kw) * 16);
#pragma unroll
                for (int fm = 0; fm < 2; ++fm)
#pragma unroll
                    for (int fn = 0; fn < 4; ++fn)
                        acc[fm][fn] = __builtin_amdgcn_mfma_f32_16x16x32_f16(
                            af[fm], bf[kc][fn], acc[fm][fn], 0, 0, 0);
            }
        }
    }

    // ---- fused squash epilogue via LDS transpose (A space is dead now) ----
    __syncthreads();  // all A reads done; Y regions may overlay A
    char* Y = smem + w_id * 8704;    // per-wave: 32 px rows x 272B (68 f32)
#pragma unroll
    for (int fm = 0; fm < 2; ++fm)
#pragma unroll
        for (int fn = 0; fn < 4; ++fn)
#pragma unroll
            for (int rg = 0; rg < 4; ++rg) {
                const int m = fm * 16 + q * 4 + rg;   // px in wave (C/D row)
                const int c = fn * 16 + m15;          // co in wave (C/D col)
                *(float*)(Y + m * 272 + c * 4) = acc[fm][fn][rg];
            }
    __syncthreads();

    const int h  = h0 + (wm >> 1);
    const int wb = (wm & 1) * 32;
#pragma unroll
    for (int it = 0; it < 2; ++it) {
        const int m   = it * 16 + m15;   // px in wave
        const int mol = q;               // local mo group (0..3)
        const float* yp = (const float*)(Y + m * 272 + mol * 64);
        float4 v0 = *(const float4*)(yp);
        float4 v1 = *(const float4*)(yp + 4);
        float4 v2 = *(const float4*)(yp + 8);
        float4 v3 = *(const float4*)(yp + 12);
        float s = 0.f;
        s = fmaf(v0.x, v0.x, s); s = fmaf(v0.y, v0.y, s);
        s = fmaf(v0.z, v0.z, s); s = fmaf(v0.w, v0.w, s);
        s = fmaf(v1.x, v1.x, s); s = fmaf(v1.y, v1.y, s);
        s = fmaf(v1.z, v1.z, s); s = fmaf(v1.w, v1.w, s);
        s = fmaf(v2.x, v2.x, s); s = fmaf(v2.y, v2.y, s);
        s = fmaf(v2.z, v2.z, s); s = fmaf(v2.w, v2.w, s);
        s = fmaf(v3.x, v3.x, s); s = fmaf(v3.y, v3.y, s);
        s = fmaf(v3.z, v3.z, s); s = fmaf(v3.w, v3.w, s);
        const float mult = s / ((1.0f + s) * sqrtf(s + EPSF));
        v0.x *= mult; v0.y *= mult; v0.z *= mult; v0.w *= mult;
        v1.x *= mult; v1.y *= mult; v1.z *= mult; v1.w *= mult;
        v2.x *= mult; v2.y *= mult; v2.z *= mult; v2.w *= mult;
        v3.x *= mult; v3.y *= mult; v3.z *= mult; v3.w *= mult;
        const int mo = wn * 4 + mol;
        float* op = out + ((((b * 8 + mo) * 64 + h) * 64 + (wb + m)) * 16);
        *(float4*)(op)      = v0;
        *(float4*)(op + 4)  = v1;
        *(float4*)(op + 8)  = v2;
        *(float4*)(op + 12) = v3;
    }
}

extern "C" void kernel_launch(void* const* d_in, const int* in_sizes, int n_in,
                              void* d_out, int out_size, void* d_ws, size_t ws_size,
                              hipStream_t stream) {
    const float* x  = (const float*)d_in[0];
    const float* cw = (const float*)d_in[1];
    const float* cb = (const float*)d_in[2];
    // d_in[3] (b_logits): routing is degenerate (softmax over broadcast size-1
    // MI axis, shift-invariant b-updates) -> out = squash(conv_out). Verified
    // empirically (rounds 2 and 8 both passed).
    float* outp    = (float*)d_out;
    _Float16* wTh  = (_Float16*)d_ws;  // 294,912 bytes

    hipFuncSetAttribute((const void*)conv_mfma_kernel,
                        hipFuncAttributeMaxDynamicSharedMemorySize, LDS_TOTAL);
    hipLaunchKernelGGL(repack_kernel, dim3(576), dim3(256), 0, stream, cw, wTh);
    hipLaunchKernelGGL(conv_mfma_kernel, dim3(256), dim3(512), LDS_TOTAL, stream,
                       x, wTh, cb, outp);
}